// Round 9
// baseline (51.305 us; speedup 1.0000x reference)
//
#include <hip/hip_runtime.h>

// LocalConv: out[b][o][oh][ow] = sum_f patch[p][b][f] * W[p][f][o]
// B=64, C=16, H=W=64, K=3x3, OH=OW=62, OUT_CH=32, FEAT=144, P=3844
// Round 9: B staged fp32 via global_load_lds (per-lane src, permuted
// [g][hi][o][cj^swz] layout) -> no VGPR ring, no ds_write phase. One
// __syncthreads per position (m97 pattern). A-slab bf16 (r4 machinery).
// TW=4 strips, 73.7KB LDS -> 2 blocks/CU.
#define CIN    16
#define HH     64
#define WW     64
#define OHD    62
#define OWD    62
#define OUTC   32
#define FEATN  144
#define POUT   (OHD*OWD)
#define BPOS   4608                    // floats per position (144*32)
#define AR_W   6                       // A slab w-dim (TW+2)
#define A_ELEMS (3*AR_W*64*16)         // 18432 ushort = 36864 B
#define SMEM_BYTES (BPOS*2*4 + A_ELEMS*2)   // 36864 + 36864 = 73728 B

typedef __attribute__((ext_vector_type(8))) short  short8;
typedef __attribute__((ext_vector_type(4))) float  f32x4;
typedef __attribute__((ext_vector_type(4), aligned(4))) float f32x4u; // unaligned store
typedef __attribute__((ext_vector_type(2), aligned(4))) float f32x2u;
typedef __attribute__((ext_vector_type(4))) unsigned u32x4;

__device__ __forceinline__ unsigned cvtpk(float a, float b) {
    unsigned r;
    asm("v_cvt_pk_bf16_f32 %0, %1, %2" : "=v"(r) : "v"(a), "v"(b));
    return r;
}
__device__ __forceinline__ short8 cvt8(f32x4 lo, f32x4 hi) {
    union { u32x4 u; short8 s; } t;
    t.u[0] = cvtpk(lo[0], lo[1]);
    t.u[1] = cvtpk(lo[2], lo[3]);
    t.u[2] = cvtpk(hi[0], hi[1]);
    t.u[3] = cvtpk(hi[2], hi[3]);
    return t.s;
}

template<int TW>
__device__ __forceinline__ void conv_body(
    const float* __restrict__ inp, const float* __restrict__ wgt,
    float* __restrict__ out, int oh, int ow0,
    float* __restrict__ Bf, unsigned short* __restrict__ Araw)
{
    const int tid = threadIdx.x;
    constexpr int WTOT = TW + 2;
    const int lane = tid & 63, wid = tid >> 6;
    const int p0 = oh * OWD + ow0;

    // ---- B stage: global_load_lds, per-lane source, linear LDS dest.
    //      LDS slot s = i*64+lane holds W element (g,hi,o,cj):
    //      gh = s>>8, o = (s>>3)&31, cjp = s&7, cj = cjp ^ (((o>>2)&1)<<2)
    //      (o>>2)&1 == (lane>>5)&1 on the write side. f = (hi*8+cj)*9 + g.
    const int cj_w = (lane & 7) ^ (((lane >> 5) & 1) << 2);
    const int orow = lane >> 3;                       // o within octet
    auto stageB = [&](int q) {
        const float* wp = wgt + (size_t)(p0 + q) * BPOS;
        float* Bb = Bf + (q & 1) * BPOS;
        #pragma unroll
        for (int k = 0; k < 9; ++k) {
            const int i  = wid * 9 + k;
            const int gh = i >> 2;                    // g*2+hi
            const int o  = ((i & 3) << 3) + orow;
            const int g  = gh >> 1, hi = gh & 1;
            const int f  = (hi * 8 + cj_w) * 9 + g;
            __builtin_amdgcn_global_load_lds(
                (const __attribute__((address_space(1))) unsigned int*)(wp + f * 32 + o),
                (__attribute__((address_space(3))) unsigned int*)(Bb + i * 64),
                4, 0, 0);
        }
    };

    stageB(0);   // issue before A staging; drained at the prologue barrier

    // ---- stage A slab (bf16 by truncation, r4-verified swizzle):
    //      granule G = ((kh*AR_W+w)*64+b)*2 + (half^((b>>2)&1)), G ^= (w&3)<<1
    for (int t = tid; t < 3 * WTOT * 64; t += 512) {
        int w   = t % WTOT;
        int rem = t / WTOT;
        int b   = rem & 63;
        int kh  = rem >> 6;
        const char* src = (const char*)(inp + (size_t)b * (CIN * HH * WW)
                        + (size_t)(oh + kh) * WW + (ow0 + w)) + 2;
        short8 h0, h1;
        #pragma unroll
        for (int c = 0; c < 8; ++c)
            h0[c] = (short)*(const unsigned short*)(src + c * (HH * WW * 4));
        #pragma unroll
        for (int c = 0; c < 8; ++c)
            h1[c] = (short)*(const unsigned short*)(src + (c + 8) * (HH * WW * 4));
        int s = (b >> 2) & 1;
        unsigned Gb = (unsigned)(((kh * AR_W + w) * 64 + b) * 2);
        unsigned wx = (unsigned)((w & 3) << 1);
        *(short8*)(Araw + (((Gb + s) ^ wx) << 3))       = h0;
        *(short8*)(Araw + (((Gb + (1 - s)) ^ wx) << 3)) = h1;
    }

    // ---- fragment addressing (r4/r6-verified A side)
    const int fr = lane & 15, fq = lane >> 4, fqh = fq >> 1;
    const int mt = wid >> 1, nt = wid & 1;           // 4 m-tiles x 2 n-tiles
    const int b  = mt * 16 + fr;
    const int gr = (fq & 1) ^ ((b >> 2) & 1);
    unsigned abase_g[5]; int kwv[5]; int bslot[5];
    #pragma unroll
    for (int kc = 0; kc < 5; ++kc) {
        int g  = 2 * kc + fqh;                 // g==9 -> A-frag zero, clamp B
        int gc = (g > 8) ? 8 : g;
        int kh = (gc * 11) >> 5;               // gc/3
        int kw = gc - 3 * kh;
        abase_g[kc] = (unsigned)(((kh * AR_W + kw) * 64 + b) * 2 + gr);
        kwv[kc]     = kw;
        bslot[kc]   = ((gc * 2 + (fq & 1)) * 32 + nt * 16 + fr) * 8;
    }
    const int xB = (fr >> 2) & 1;              // B-read half-swap select

    __syncthreads();   // A slab + B(0) ready

    f32x4 acc[TW];
    #pragma unroll
    for (int q = 0; q < TW; ++q) acc[q] = (f32x4){0.f, 0.f, 0.f, 0.f};

    // ---- main loop: stageB(q+1) | frags+MFMA(q) | barrier (drains loads)
    #pragma unroll
    for (int q = 0; q < TW; ++q) {
        if (q + 1 < TW) stageB(q + 1);
        const float* Bc = Bf + (q & 1) * BPOS;
        #pragma unroll
        for (int kc = 0; kc < 5; ++kc) {
            short8 a;
            if (kc == 4 && fqh == 1) {
                a = (short8){0, 0, 0, 0, 0, 0, 0, 0};   // K pad [144,160)
            } else {
                unsigned gi = (abase_g[kc] + (unsigned)(q * 128))
                            ^ (unsigned)(((q + kwv[kc]) & 3) << 1);
                a = *(const short8*)(Araw + (gi << 3));
            }
            const float* bb = Bc + bslot[kc];
            f32x4 lo = *(const f32x4*)(bb + (xB << 2));        // j = 0..3
            f32x4 hi = *(const f32x4*)(bb + ((xB ^ 1) << 2));  // j = 4..7
            short8 bv = cvt8(lo, hi);
            acc[q] = __builtin_amdgcn_mfma_f32_16x16x32_bf16(a, bv, acc[q], 0, 0, 0);
        }
        if (q + 1 < TW) __syncthreads();
    }

    // ---- epilogue: lane owns (b_out = mt*16+fq*4+r, o = nt*16+fr),
    //      TW consecutive floats along ow
    const int o = nt * 16 + fr;
    #pragma unroll
    for (int r = 0; r < 4; ++r) {
        float* dst = out + ((size_t)((mt * 16 + fq * 4 + r) * OUTC + o)) * POUT
                         + (size_t)oh * OWD + ow0;
        if constexpr (TW == 4) {
            f32x4u v = { acc[0][r], acc[1][r], acc[2][r], acc[3][r] };
            *(f32x4u*)dst = v;
        } else {
            f32x2u v = { acc[0][r], acc[1][r] };
            *(f32x2u*)dst = v;
        }
    }
}

__global__ __launch_bounds__(512, 4) void localconv_kernel(
    const float* __restrict__ inp,
    const float* __restrict__ wgt,
    float* __restrict__ out)
{
    extern __shared__ unsigned short smem[];
    float*          Bf   = (float*)smem;                       // 36864 B
    unsigned short* Araw = smem + BPOS * 2 * 2;                // 36864 B

    // chunked XCD swizzle: 992 = 8*124; XCD x gets contiguous l range
    const int bid = blockIdx.x;
    const int l   = (bid & 7) * 124 + (bid >> 3);
    const int oh    = l >> 4;          // 0..61
    const int strip = l & 15;          // 0..15

    if (strip < 15) conv_body<4>(inp, wgt, out, oh, strip * 4, Bf, Araw);
    else            conv_body<2>(inp, wgt, out, oh, 60, Bf, Araw);
}

extern "C" void kernel_launch(void* const* d_in, const int* in_sizes, int n_in,
                              void* d_out, int out_size, void* d_ws, size_t ws_size,
                              hipStream_t stream) {
    const float* inp = (const float*)d_in[0];
    const float* wgt = (const float*)d_in[1];
    float* out = (float*)d_out;
    hipFuncSetAttribute((const void*)localconv_kernel,
                        hipFuncAttributeMaxDynamicSharedMemorySize, SMEM_BYTES);
    localconv_kernel<<<dim3(992), 512, SMEM_BYTES, stream>>>(inp, wgt, out);
}

// Round 10
// 43.928 us; speedup vs baseline: 1.1679x; 1.1679x over previous
//
#include <hip/hip_runtime.h>

// LocalConv: out[b][o][oh][ow] = sum_f patch[p][b][f] * W[p][f][o]
// B=64, C=16, H=W=64, K=3x3, OH=OW=62, OUT_CH=32, FEAT=144, P=3844
// Round 10: r6 structure, TW=4, 56.4KB static LDS -> 2 blocks/CU.
// ALL weight loads issued in prologue (depth-4 ring, no in-loop issue).
// Raw lgkmcnt(0)+s_barrier (no vmcnt drain, no sched pins) per position.
// K permuted: f'' = (kh*3+kw)*16 + c ; f = c*9 + g.
#define CIN    16
#define HH     64
#define WW     64
#define OHD    62
#define OWD    62
#define OUTC   32
#define FEATN  144
#define POUT   (OHD*OWD)
#define LSTRB  152                      // B row stride: 144 real + 8 zero pad
#define AR_W   6                        // A slab w-dim (TW+2 max)
#define AR_ELEMS   (3*AR_W*64*16)       // 18432 elems = 36864 B
#define BBUF_ELEMS (OUTC*LSTRB + 8)     // 4872 (last 8 = zero guard)

typedef __attribute__((ext_vector_type(8))) short  short8;
typedef __attribute__((ext_vector_type(4))) float  f32x4;
typedef __attribute__((ext_vector_type(4), aligned(4))) float f32x4u;
typedef __attribute__((ext_vector_type(2), aligned(4))) float f32x2u;

__device__ __forceinline__ unsigned short f2bf(float f) {
    unsigned int u = __float_as_uint(f);
    u += 0x7FFFu + ((u >> 16) & 1u);   // RNE
    return (unsigned short)(u >> 16);
}

// barrier without vmcnt drain: waits own LDS ops, leaves global loads in flight.
// Single asm block so nothing is scheduled between the wait and the barrier;
// "memory" clobber orders all LDS/global accesses across it.
__device__ __forceinline__ void softBarrier() {
    asm volatile("s_waitcnt lgkmcnt(0)\n\ts_barrier" ::: "memory");
}

template<int TW>
__device__ __forceinline__ void conv_body(
    const float* __restrict__ inp, const float* __restrict__ wgt,
    float* __restrict__ out, int oh, int ow0,
    unsigned short* __restrict__ Araw, unsigned short* __restrict__ B_lds)
{
    const int tid = threadIdx.x;
    constexpr int WTOT = TW + 2;

    // ---- weight stream: thread = (o_w = tid&31, c_w = tid>>5 in 0..15).
    //      9 f32 loads/thread/position (f = c_w*9 + g); each wave-instr =
    //      2 dense 128B lines. ALL TW positions issued in the prologue.
    const int o_w = tid & 31;
    const int c_w = tid >> 5;
    const int p0  = oh * OWD + ow0;
    const float* wbase = wgt + (size_t)p0 * (FEATN * OUTC) + c_w * 288 + o_w;
    float ring[4][9];
    auto issue = [&](int t) {            // t compile-time under full unroll
        const float* p = wbase + (size_t)t * (FEATN * OUTC);
        #pragma unroll
        for (int g = 0; g < 9; ++g) ring[t & 3][g] = p[g * 32];
    };
    const int wb_base = o_w * LSTRB + c_w;     // + g*16
    auto writeB = [&](int t, unsigned short* Bb) {
        #pragma unroll
        for (int g = 0; g < 9; ++g)
            Bb[wb_base + g * 16] = f2bf(ring[t & 3][g]);
    };

    // ---- prologue: issue ALL weight loads (latency absorbed once per block)
    issue(0);
    if (TW > 1) issue(1);
    if (TW > 2) issue(2);
    if (TW > 3) issue(3);

    // ---- stage A slab: Araw granule G = ((kh*AR_W+w)*64+b)*2 + gr, swizzled
    //      gr = half ^ ((b>>2)&1); G ^= (w&3)<<1  (spreads write banks)
    for (int t = tid; t < 3 * WTOT * 64; t += 512) {
        int w   = t % WTOT;
        int rem = t / WTOT;
        int b   = rem & 63;
        int kh  = rem >> 6;
        const float* src = inp + (size_t)b * (CIN * HH * WW)
                               + (size_t)(oh + kh) * WW + (ow0 + w);
        short8 h0, h1;
        #pragma unroll
        for (int c = 0; c < 8; ++c) h0[c] = (short)f2bf(src[c * (HH * WW)]);
        #pragma unroll
        for (int c = 0; c < 8; ++c) h1[c] = (short)f2bf(src[(c + 8) * (HH * WW)]);
        int s = (b >> 2) & 1;
        unsigned Gb = (unsigned)(((kh * AR_W + w) * 64 + b) * 2);
        unsigned wx = (unsigned)((w & 3) << 1);
        *(short8*)(Araw + (((Gb + s) ^ wx) << 3))       = h0;
        *(short8*)(Araw + (((Gb + (1 - s)) ^ wx) << 3)) = h1;
    }

    // ---- zero B pad [144,152) per row + 8-elem guard, both buffers
    for (int t = tid; t < 2 * 264; t += 512) {
        int buf = t / 264, r = t % 264;
        int e = (r < 256) ? ((r >> 3) * LSTRB + 144 + (r & 7))
                          : (OUTC * LSTRB + (r & 7));
        B_lds[buf * BBUF_ELEMS + e] = 0;
    }

    writeB(0, B_lds);          // buf0 <- q0 (counted vmcnt via reg dep)

    // ---- fragment addressing (r4/r6-verified)
    const int wid = tid >> 6, lane = tid & 63;
    const int fr = lane & 15, fq = lane >> 4, fqh = fq >> 1;
    const int mt = wid >> 1, nt = wid & 1;           // 4 m-tiles x 2 n-tiles
    const int b  = mt * 16 + fr;
    const int gr = (fq & 1) ^ ((b >> 2) & 1);
    unsigned abase_g[5]; int kwv[5]; int boff[5];
    #pragma unroll
    for (int kc = 0; kc < 5; ++kc) {
        int g  = 2 * kc + fqh;                 // 9 -> pad (zero A-frag)
        int gc = (g > 8) ? 8 : g;
        int kh = (gc * 11) >> 5;               // gc/3
        int kw = gc - 3 * kh;
        abase_g[kc] = (unsigned)(((kh * AR_W + kw) * 64 + b) * 2 + gr);
        kwv[kc]     = kw;
        boff[kc]    = (nt * 16 + fr) * LSTRB + kc * 32 + fq * 8;
    }

    softBarrier();   // A slab + B buf0 ready; remaining loads stay in flight

    f32x4 acc[TW];
    #pragma unroll
    for (int q = 0; q < TW; ++q) acc[q] = (f32x4){0.f, 0.f, 0.f, 0.f};

    // ---- main loop: MFMA(q) | writeB(q+1) | soft barrier  (no vmcnt drain)
    #pragma unroll
    for (int q = 0; q < TW; ++q) {
        const unsigned short* Bc = B_lds + (q & 1) * BBUF_ELEMS;
        #pragma unroll
        for (int kc = 0; kc < 5; ++kc) {
            short8 a;
            if (kc == 4 && fqh == 1) {
                a = (short8){0, 0, 0, 0, 0, 0, 0, 0};   // K in [144,160): A=0
            } else {
                unsigned gi = (abase_g[kc] + (unsigned)(q * 128))
                              ^ (unsigned)(((q + kwv[kc]) & 3) << 1);
                a = *(const short8*)(Araw + (gi << 3));
            }
            short8 bfv = *(const short8*)(Bc + boff[kc]);
            acc[q] = __builtin_amdgcn_mfma_f32_16x16x32_bf16(a, bfv, acc[q], 0, 0, 0);
        }
        if (q + 1 < TW) {
            writeB(q + 1, B_lds + ((q + 1) & 1) * BBUF_ELEMS);
            softBarrier();
        }
    }

    // ---- epilogue: lane owns (b_out = mt*16+fq*4+r, o = nt*16+fr),
    //      TW consecutive floats along ow
    const int o = nt * 16 + fr;
    #pragma unroll
    for (int r = 0; r < 4; ++r) {
        float* dst = out + ((size_t)((mt * 16 + fq * 4 + r) * OUTC + o)) * POUT
                         + (size_t)oh * OWD + ow0;
        if constexpr (TW == 4) {
            f32x4u v = { acc[0][r], acc[1][r], acc[2][r], acc[3][r] };
            *(f32x4u*)dst = v;
        } else {
            f32x2u v = { acc[0][r], acc[1][r] };
            *(f32x2u*)dst = v;
        }
    }
}

__global__ __launch_bounds__(512, 4) void localconv_kernel(
    const float* __restrict__ inp,
    const float* __restrict__ wgt,
    float* __restrict__ out)
{
    __shared__ unsigned short Araw[AR_ELEMS];            // 36864 B
    __shared__ unsigned short B_lds[2 * BBUF_ELEMS];     // 19488 B  (total 56352)

    // chunked XCD swizzle: 992 = 8*124; XCD x gets contiguous l in [124x,124x+124)
    const int bid = blockIdx.x;
    const int l   = (bid & 7) * 124 + (bid >> 3);
    const int oh    = l >> 4;          // 0..61
    const int strip = l & 15;          // 0..15

    if (strip < 15) conv_body<4>(inp, wgt, out, oh, strip * 4, Araw, B_lds);
    else            conv_body<2>(inp, wgt, out, oh, 60, Araw, B_lds);
}

extern "C" void kernel_launch(void* const* d_in, const int* in_sizes, int n_in,
                              void* d_out, int out_size, void* d_ws, size_t ws_size,
                              hipStream_t stream) {
    const float* inp = (const float*)d_in[0];
    const float* wgt = (const float*)d_in[1];
    float* out = (float*)d_out;
    localconv_kernel<<<dim3(992), 512, 0, stream>>>(inp, wgt, out);
}